// Round 1
// baseline (1063.832 us; speedup 1.0000x reference)
//
#include <hip/hip_runtime.h>
#include <math.h>

#define NN 100000      // nodes
#define NE 1600000     // edges
#define NG 512         // graphs
#define LN_EPS 1e-5f

typedef __attribute__((ext_vector_type(8))) short short8;
typedef __attribute__((ext_vector_type(8))) unsigned short ushort8;
typedef __attribute__((ext_vector_type(4))) float floatx4;

union BF8 { short8 v; short s[8]; };
union U8  { ushort8 v; unsigned short s[8]; };
union F4  { floatx4 v; float f[4]; };

static __device__ __forceinline__ short f2bf(float f) {
    union { float f; unsigned u; } a; a.f = f;
    unsigned u = a.u;
    unsigned r = (u + 0x7fffu + ((u >> 16) & 1u)) >> 16;   // RNE
    return (short)r;
}
static __device__ __forceinline__ float bf2f(unsigned short h) {
    union { unsigned u; float f; } a; a.u = ((unsigned)h) << 16;
    return a.f;
}
static __device__ __forceinline__ float silu_f(float v) {
    return v / (1.0f + __expf(-v));
}

// ---------------------------------------------------------------------------
// Edge kernel: per wave, one 16-edge x 64-col tile.
//   EA  = silu(edge_attr @ We + be)          (MFMA 1)
//   T   = relu(x[src] + EA)                  (LDS C->A layout round-trip)
//   msg = silu(T @ Wm + bm)                  (MFMA 2)
//   atomicAdd into agg[dst]
// mfma_f32_16x16x32_bf16 layouts (HW-verified):
//   A: m = lane&15, k = (lane>>4)*8 + j
//   B: n = lane&15, k = (lane>>4)*8 + j
//   C/D: col = lane&15, row = (lane>>4)*4 + reg
// ---------------------------------------------------------------------------
__global__ __launch_bounds__(256)
void edge_kernel(const float* __restrict__ x,
                 const int* __restrict__ src,
                 const int* __restrict__ dst,
                 const float* __restrict__ eattr,
                 const float* __restrict__ We,
                 const float* __restrict__ be,
                 const float* __restrict__ Wm,
                 const float* __restrict__ bm,
                 float* __restrict__ agg)
{
    __shared__ unsigned short lds[4][16 * 72];   // wave-private 16x64 bf16 tile, +8 pad
    const int lane = threadIdx.x & 63;
    const int wid  = threadIdx.x >> 6;
    const int m = lane & 15;
    const int q = lane >> 4;
    unsigned short* tile = lds[wid];

    // Stage B-fragments of We and Wm in registers (column tile t covers cols 16t..16t+15)
    short8 wef[2][4], wmf[2][4];
    float bev[4], bmv[4];
    #pragma unroll
    for (int kh = 0; kh < 2; ++kh) {
        #pragma unroll
        for (int t = 0; t < 4; ++t) {
            BF8 fe, fm;
            #pragma unroll
            for (int j = 0; j < 8; ++j) {
                const int k = kh * 32 + q * 8 + j;
                const int n = m + 16 * t;
                fe.s[j] = f2bf(We[k * 64 + n]);
                fm.s[j] = f2bf(Wm[k * 64 + n]);
            }
            wef[kh][t] = fe.v; wmf[kh][t] = fm.v;
        }
    }
    #pragma unroll
    for (int t = 0; t < 4; ++t) { bev[t] = be[m + 16 * t]; bmv[t] = bm[m + 16 * t]; }

    const int n_tiles = NE / 16;
    const int stride  = gridDim.x * 4;
    for (int tl = blockIdx.x * 4 + wid; tl < n_tiles; tl += stride) {
        const int e0 = tl * 16;

        // ---- matmul 1: A = edge_attr tile ----
        short8 a1[2];
        #pragma unroll
        for (int kh = 0; kh < 2; ++kh) {
            const float* p = eattr + (size_t)(e0 + m) * 64 + kh * 32 + q * 8;
            F4 v0, v1; v0.v = *(const floatx4*)p; v1.v = *(const floatx4*)(p + 4);
            BF8 f;
            #pragma unroll
            for (int j = 0; j < 4; ++j) { f.s[j] = f2bf(v0.f[j]); f.s[j + 4] = f2bf(v1.f[j]); }
            a1[kh] = f.v;
        }
        floatx4 acc[4];
        #pragma unroll
        for (int t = 0; t < 4; ++t) acc[t] = (floatx4){0.f, 0.f, 0.f, 0.f};
        #pragma unroll
        for (int kh = 0; kh < 2; ++kh)
            #pragma unroll
            for (int t = 0; t < 4; ++t)
                acc[t] = __builtin_amdgcn_mfma_f32_16x16x32_bf16(a1[kh], wef[kh][t], acc[t], 0, 0, 0);

        // silu + bias, write EA to LDS (C-layout -> row-major bf16 tile)
        #pragma unroll
        for (int t = 0; t < 4; ++t)
            #pragma unroll
            for (int r = 0; r < 4; ++r) {
                const float v = silu_f(acc[t][r] + bev[t]);
                tile[(q * 4 + r) * 72 + m + 16 * t] = (unsigned short)f2bf(v);
            }
        __asm__ volatile("s_waitcnt lgkmcnt(0)" ::: "memory");  // wave-synchronous LDS RAW

        // ---- matmul 2: A = relu(x[src] + EA) ----
        const int sn = src[e0 + m];
        short8 a2[2];
        #pragma unroll
        for (int kh = 0; kh < 2; ++kh) {
            U8 t8; t8.v = *(const ushort8*)&tile[m * 72 + kh * 32 + q * 8];
            const float* xp = x + (size_t)sn * 64 + kh * 32 + q * 8;
            F4 x0, x1; x0.v = *(const floatx4*)xp; x1.v = *(const floatx4*)(xp + 4);
            BF8 f;
            #pragma unroll
            for (int j = 0; j < 4; ++j) {
                f.s[j]     = f2bf(fmaxf(bf2f(t8.s[j])     + x0.f[j], 0.0f));
                f.s[j + 4] = f2bf(fmaxf(bf2f(t8.s[j + 4]) + x1.f[j], 0.0f));
            }
            a2[kh] = f.v;
        }
        #pragma unroll
        for (int t = 0; t < 4; ++t) acc[t] = (floatx4){0.f, 0.f, 0.f, 0.f};
        #pragma unroll
        for (int kh = 0; kh < 2; ++kh)
            #pragma unroll
            for (int t = 0; t < 4; ++t)
                acc[t] = __builtin_amdgcn_mfma_f32_16x16x32_bf16(a2[kh], wmf[kh][t], acc[t], 0, 0, 0);

        // silu + bias, scatter-add to agg[dst]
        int dn[4];
        #pragma unroll
        for (int r = 0; r < 4; ++r) dn[r] = dst[e0 + q * 4 + r];
        #pragma unroll
        for (int t = 0; t < 4; ++t)
            #pragma unroll
            for (int r = 0; r < 4; ++r) {
                const float v = silu_f(acc[t][r] + bmv[t]);
                atomicAdd(agg + (size_t)dn[r] * 64 + (m + 16 * t), v);
            }
    }
}

// ---------------------------------------------------------------------------
// Stats: per-graph sum / sumsq / node-count over pre = agg + (1+eps)*x.
// One wave per node (lane = channel), shuffle reduce, 3 atomics per node.
// ---------------------------------------------------------------------------
__global__ __launch_bounds__(256)
void stats_kernel(const float* __restrict__ agg,
                  const float* __restrict__ x,
                  const int* __restrict__ n2g,
                  const float* __restrict__ eps,
                  float* __restrict__ gsum,
                  float* __restrict__ gss,
                  float* __restrict__ gcnt)
{
    const int lane = threadIdx.x & 63;
    const int wid  = threadIdx.x >> 6;
    const float k = 1.0f + eps[0];
    const int stride = gridDim.x * 4;
    for (int n = blockIdx.x * 4 + wid; n < NN; n += stride) {
        const float pre = agg[(size_t)n * 64 + lane] + k * x[(size_t)n * 64 + lane];
        float s = pre, ss = pre * pre;
        #pragma unroll
        for (int off = 32; off > 0; off >>= 1) {
            s  += __shfl_down(s, off, 64);
            ss += __shfl_down(ss, off, 64);
        }
        if (lane == 0) {
            const int g = n2g[n];
            atomicAdd(&gsum[g], s);
            atomicAdd(&gss[g], ss);
            atomicAdd(&gcnt[g], 1.0f);
        }
    }
}

// ---------------------------------------------------------------------------
// Norm + residual + relu, in place over the agg buffer (== d_out).
// ---------------------------------------------------------------------------
__global__ __launch_bounds__(256)
void norm_kernel(const float* __restrict__ x,
                 const int* __restrict__ n2g,
                 const float* __restrict__ eps,
                 const float* __restrict__ gamma,
                 const float* __restrict__ beta,
                 const float* __restrict__ gsum,
                 const float* __restrict__ gss,
                 const float* __restrict__ gcnt,
                 float* __restrict__ out)   // holds agg on entry
{
    const float k = 1.0f + eps[0];
    const int total = NN * 16;               // float4 granules
    for (int idx = blockIdx.x * blockDim.x + threadIdx.x; idx < total;
         idx += gridDim.x * blockDim.x) {
        const int n  = idx >> 4;
        const int c4 = (idx & 15) * 4;
        const int g  = n2g[n];
        const float cnt  = fmaxf(gcnt[g] * 64.0f, 1.0f);
        const float mean = gsum[g] / cnt;
        const float var  = gss[g] / cnt - mean * mean;
        const float rsig = rsqrtf(var + LN_EPS);
        F4 a, xv, o;
        a.v  = *(const floatx4*)&out[(size_t)n * 64 + c4];
        xv.v = *(const floatx4*)&x[(size_t)n * 64 + c4];
        #pragma unroll
        for (int j = 0; j < 4; ++j) {
            const float pre = a.f[j] + k * xv.f[j];
            const float v = (pre - mean) * rsig * gamma[c4 + j] + beta[c4 + j] + xv.f[j];
            o.f[j] = fmaxf(v, 0.0f);
        }
        *(floatx4*)&out[(size_t)n * 64 + c4] = o.v;
    }
}

extern "C" void kernel_launch(void* const* d_in, const int* in_sizes, int n_in,
                              void* d_out, int out_size, void* d_ws, size_t ws_size,
                              hipStream_t stream)
{
    const float* x      = (const float*)d_in[0];
    const int*   ei     = (const int*)  d_in[1];
    const float* eattr  = (const float*)d_in[2];
    const int*   n2g    = (const int*)  d_in[3];
    // branch-1 params (d_in[4..10]) are dead in the reference: conv1's result is
    // overwritten by conv2(x, ...). Only branch 2 affects the output.
    const float* We2    = (const float*)d_in[11];
    const float* be2    = (const float*)d_in[12];
    const float* Wm2    = (const float*)d_in[13];
    const float* bm2    = (const float*)d_in[14];
    const float* eps2   = (const float*)d_in[15];
    const float* gamma2 = (const float*)d_in[16];
    const float* beta2  = (const float*)d_in[17];

    float* out  = (float*)d_out;           // doubles as agg scratch (same size)
    float* gsum = (float*)d_ws;            // per-graph accumulators in ws (6 KB)
    float* gss  = gsum + NG;
    float* gcnt = gss + NG;

    hipMemsetAsync(d_out, 0, (size_t)NN * 64 * sizeof(float), stream);
    hipMemsetAsync(d_ws, 0, 3 * NG * sizeof(float), stream);

    edge_kernel<<<dim3(2048), dim3(256), 0, stream>>>(
        x, ei, ei + NE, eattr, We2, be2, Wm2, bm2, out);
    stats_kernel<<<dim3(1024), dim3(256), 0, stream>>>(
        out, x, n2g, eps2, gsum, gss, gcnt);
    norm_kernel<<<dim3(1024), dim3(256), 0, stream>>>(
        x, n2g, eps2, gamma2, beta2, gsum, gss, gcnt, out);
}